// Round 5
// baseline (171.234 us; speedup 1.0000x reference)
//
#include <hip/hip_runtime.h>
#include <hip/hip_cooperative_groups.h>
#include <math.h>

namespace cg = cooperative_groups;

constexpr int N = 4096;
constexpr int D = 256;
constexpr int KMAX = 32;           // safe bound on directed degree (Poisson(~6))
constexpr int BLOCKS = 256;        // 1 block per CU -> co-resident
constexpr int TPB = 1024;          // 16 waves/block; 4096 waves total = one per row

__device__ inline int lower_bound(const int* __restrict__ a, int n, int key) {
    int lo = 0, hi = n;
    while (lo < hi) {
        int mid = (lo + hi) >> 1;
        if (a[mid] < key) lo = mid + 1; else hi = mid;
    }
    return lo;
}

__device__ inline void spmm_wave(int r, int lane, const int* __restrict__ deg,
                                 const int* __restrict__ ell,
                                 const float* __restrict__ X, float* __restrict__ Y) {
    int dcnt = deg[r];
    int cnt = dcnt > KMAX ? KMAX : dcnt;
    float dr = rsqrtf((float)dcnt + 1.0f);
    const float4 xs = *reinterpret_cast<const float4*>(&X[(size_t)r * D + lane * 4]);
    float w0 = dr * dr;                 // implicit self loop
    float4 acc;
    acc.x = w0 * xs.x; acc.y = w0 * xs.y; acc.z = w0 * xs.z; acc.w = w0 * xs.w;

    int   c_l = 0;
    float w_l = 0.0f;
    if (lane < cnt) {
        c_l = ell[r * KMAX + lane];
        w_l = dr * rsqrtf((float)deg[c_l] + 1.0f);
    }
    for (int k = 0; k < cnt; ++k) {
        int   c = __shfl(c_l, k);
        float w = __shfl(w_l, k);
        const float4 x = *reinterpret_cast<const float4*>(&X[(size_t)c * D + lane * 4]);
        acc.x += w * x.x; acc.y += w * x.y; acc.z += w * x.z; acc.w += w * x.w;
    }
    *reinterpret_cast<float4*>(&Y[(size_t)r * D + lane * 4]) = acc;
}

__global__ __launch_bounds__(TPB) void k_all(
        const int* __restrict__ row, const int* __restrict__ col, int nnz_e,
        const float* __restrict__ X,
        const int* __restrict__ member_nodes, const int* __restrict__ comm_ids,
        int M, int C, const int* __restrict__ comm_owner,
        int* __restrict__ deg, int* __restrict__ ell,
        float* __restrict__ y1, float* __restrict__ prop,
        int* __restrict__ start, int* __restrict__ ostart,
        float* __restrict__ out) {
    cg::grid_group grid = cg::this_grid();
    const int tid = blockIdx.x * TPB + threadIdx.x;
    const int nthreads = BLOCKS * TPB;
    const int wid = tid >> 6;          // 0..4095 : one wave per row/node
    const int lane = threadIdx.x & 63;

    // ---- P0: zero degree + segment-boundary binary searches (input-only) ----
    if (tid < N) deg[tid] = 0;
    for (int t = tid; t <= C; t += nthreads) start[t] = lower_bound(comm_ids, M, t);
    for (int t = tid; t <= N; t += nthreads) ostart[t] = lower_bound(comm_owner, C, t);
    grid.sync();

    // ---- P1: ELL build (atomic slot scatter) ----
    for (int e = tid; e < nnz_e; e += nthreads) {
        int r = row[e], c = col[e];
        int pos = atomicAdd(&deg[r], 1);
        if (pos < KMAX) ell[r * KMAX + pos] = c;
    }
    grid.sync();

    // ---- P2: y1 = S @ X ----
    spmm_wave(wid, lane, deg, ell, X, y1);
    grid.sync();

    // ---- P3: prop = S @ y1 ----
    spmm_wave(wid, lane, deg, ell, y1, prop);
    grid.sync();

    // ---- P4: community mean + owner max + fallback + relu + concat ----
    {
        const int v = wid;
        const float4 p = *reinterpret_cast<const float4*>(&prop[(size_t)v * D + lane * 4]);
        int cs = ostart[v], ce = ostart[v + 1];
        float4 second;
        if (cs == ce) {
            second = p;                // no community: fallback to prop
        } else {
            float4 mx = make_float4(-INFINITY, -INFINITY, -INFINITY, -INFINITY);
            for (int c = cs; c < ce; ++c) {
                int ms = start[c], me = start[c + 1];
                float4 sum = make_float4(0.f, 0.f, 0.f, 0.f);
                int m = ms;
                for (; m + 1 < me; m += 2) {
                    int n0 = member_nodes[m], n1 = member_nodes[m + 1];
                    const float4 x0 = *reinterpret_cast<const float4*>(&prop[(size_t)n0 * D + lane * 4]);
                    const float4 x1 = *reinterpret_cast<const float4*>(&prop[(size_t)n1 * D + lane * 4]);
                    sum.x += x0.x + x1.x; sum.y += x0.y + x1.y;
                    sum.z += x0.z + x1.z; sum.w += x0.w + x1.w;
                }
                if (m < me) {
                    int n0 = member_nodes[m];
                    const float4 x0 = *reinterpret_cast<const float4*>(&prop[(size_t)n0 * D + lane * 4]);
                    sum.x += x0.x; sum.y += x0.y; sum.z += x0.z; sum.w += x0.w;
                }
                float inv = 1.0f / (float)(me - ms);
                mx.x = fmaxf(mx.x, sum.x * inv); mx.y = fmaxf(mx.y, sum.y * inv);
                mx.z = fmaxf(mx.z, sum.z * inv); mx.w = fmaxf(mx.w, sum.w * inv);
            }
            second = mx;
        }
        float4 first;
        first.x = fmaxf(p.x, 0.f); first.y = fmaxf(p.y, 0.f);
        first.z = fmaxf(p.z, 0.f); first.w = fmaxf(p.w, 0.f);
        second.x = fmaxf(second.x, 0.f); second.y = fmaxf(second.y, 0.f);
        second.z = fmaxf(second.z, 0.f); second.w = fmaxf(second.w, 0.f);
        *reinterpret_cast<float4*>(&out[(size_t)v * (2 * D) + lane * 4]) = first;
        *reinterpret_cast<float4*>(&out[(size_t)v * (2 * D) + D + lane * 4]) = second;
    }
}

extern "C" void kernel_launch(void* const* d_in, const int* in_sizes, int n_in,
                              void* d_out, int out_size, void* d_ws, size_t ws_size,
                              hipStream_t stream) {
    const int*   edge_index   = (const int*)d_in[0];
    const float* X            = (const float*)d_in[1];
    const int*   member_nodes = (const int*)d_in[2];
    const int*   comm_ids     = (const int*)d_in[3];
    const int*   comm_owner   = (const int*)d_in[4];

    int nnz_e = in_sizes[0] / 2;
    int M     = in_sizes[2];
    int C     = in_sizes[4];

    const int ND = N * D;
    int* ws = (int*)d_ws;
    int off = 0;
    int*   deg    = ws + off; off += N;
    int*   ell    = ws + off; off += N * KMAX;
    off = (off + 3) & ~3;                        // 16B align for float4
    float* y1     = (float*)(ws + off); off += ND;
    float* prop   = (float*)(ws + off); off += ND;
    int*   start  = ws + off; off += C + 1;
    int*   ostart = ws + off; off += N + 1;

    const int* row = edge_index;
    const int* col = edge_index + nnz_e;
    float* outp = (float*)d_out;

    void* args[] = {
        (void*)&row, (void*)&col, (void*)&nnz_e,
        (void*)&X,
        (void*)&member_nodes, (void*)&comm_ids,
        (void*)&M, (void*)&C, (void*)&comm_owner,
        (void*)&deg, (void*)&ell,
        (void*)&y1, (void*)&prop,
        (void*)&start, (void*)&ostart,
        (void*)&outp,
    };
    hipLaunchCooperativeKernel((void*)k_all, dim3(BLOCKS), dim3(TPB), args, 0, stream);
}

// Round 6
// 46.501 us; speedup vs baseline: 3.6824x; 3.6824x over previous
//
#include <hip/hip_runtime.h>
#include <math.h>

constexpr int N = 4096;
constexpr int D = 256;
constexpr int KMAX = 32;             // safe bound on directed degree (Poisson(~6))
constexpr int ROW_BLOCKS = N / 4;    // 4 waves (rows) per 256-thread block

// ---------------- zero degree counters ----------------
__global__ void k_zero(int* __restrict__ deg) {
    int i = blockIdx.x * blockDim.x + threadIdx.x;
    if (i < N) deg[i] = 0;
}

__device__ inline int lower_bound(const int* __restrict__ a, int n, int key) {
    int lo = 0, hi = n;
    while (lo < hi) {
        int mid = (lo + hi) >> 1;
        if (a[mid] < key) lo = mid + 1; else hi = mid;
    }
    return lo;
}

// ---------------- ELL build (atomic slot scatter) + segment bounds ----------------
__global__ void k_build(const int* __restrict__ row, const int* __restrict__ col,
                        int nnz_e, int* __restrict__ deg, int* __restrict__ ell,
                        const int* __restrict__ comm_ids, int M, int C,
                        int* __restrict__ start,
                        const int* __restrict__ comm_owner, int* __restrict__ ostart) {
    int t = blockIdx.x * blockDim.x + threadIdx.x;
    if (t < nnz_e) {
        int r = row[t], c = col[t];
        int pos = atomicAdd(&deg[r], 1);
        if (pos < KMAX) ell[r * KMAX + pos] = c;
    }
    if (t <= C) start[t] = lower_bound(comm_ids, M, t);
    if (t <= N) ostart[t] = lower_bound(comm_owner, C, t);
}

// ---------------- ELL SpMM (gather): wave per row, 2 independent accumulators ----------------
__global__ __launch_bounds__(256) void k_spmm(const int* __restrict__ deg,
                                              const int* __restrict__ ell,
                                              const float* __restrict__ X,
                                              float* __restrict__ Y) {
    int r = blockIdx.x * 4 + (threadIdx.x >> 6);
    int lane = threadIdx.x & 63;
    int dcnt = deg[r];
    int cnt = dcnt > KMAX ? KMAX : dcnt;
    float dr = rsqrtf((float)dcnt + 1.0f);

    const float4 xs = *reinterpret_cast<const float4*>(&X[(size_t)r * D + lane * 4]);
    float w0 = dr * dr;              // implicit self loop
    float4 acc0, acc1;
    acc0.x = w0 * xs.x; acc0.y = w0 * xs.y; acc0.z = w0 * xs.z; acc0.w = w0 * xs.w;
    acc1.x = 0.f; acc1.y = 0.f; acc1.z = 0.f; acc1.w = 0.f;

    int   c_l = 0;
    float w_l = 0.0f;
    if (lane < cnt) {
        c_l = ell[r * KMAX + lane];
        w_l = dr * rsqrtf((float)deg[c_l] + 1.0f);
    }
    int k = 0;
    for (; k + 1 < cnt; k += 2) {
        int   c0 = __shfl(c_l, k),     c1 = __shfl(c_l, k + 1);
        float w0_ = __shfl(w_l, k),    w1_ = __shfl(w_l, k + 1);
        const float4 x0 = *reinterpret_cast<const float4*>(&X[(size_t)c0 * D + lane * 4]);
        const float4 x1 = *reinterpret_cast<const float4*>(&X[(size_t)c1 * D + lane * 4]);
        acc0.x += w0_ * x0.x; acc0.y += w0_ * x0.y; acc0.z += w0_ * x0.z; acc0.w += w0_ * x0.w;
        acc1.x += w1_ * x1.x; acc1.y += w1_ * x1.y; acc1.z += w1_ * x1.z; acc1.w += w1_ * x1.w;
    }
    if (k < cnt) {
        int   c0 = __shfl(c_l, k);
        float w0_ = __shfl(w_l, k);
        const float4 x0 = *reinterpret_cast<const float4*>(&X[(size_t)c0 * D + lane * 4]);
        acc0.x += w0_ * x0.x; acc0.y += w0_ * x0.y; acc0.z += w0_ * x0.z; acc0.w += w0_ * x0.w;
    }
    acc0.x += acc1.x; acc0.y += acc1.y; acc0.z += acc1.z; acc0.w += acc1.w;
    *reinterpret_cast<float4*>(&Y[(size_t)r * D + lane * 4]) = acc0;
}

// ---------------- fused community mean + owner max + fallback + relu + concat ----------------
// 2 waves per node (interleaved member split), LDS combine; 2 nodes per 256-thread block.
__global__ __launch_bounds__(256) void k_owner(const int* __restrict__ member_nodes,
                                               const int* __restrict__ start,
                                               const int* __restrict__ ostart,
                                               const float* __restrict__ prop,
                                               float* __restrict__ out) {
    __shared__ float4 part[4][64];
    int wave = threadIdx.x >> 6;         // 0..3
    int lane = threadIdx.x & 63;
    int half = wave & 1;                 // which half of the member list
    int v = blockIdx.x * 2 + (wave >> 1);
    int cs = ostart[v], ce = ostart[v + 1];
    int single = (ce - cs == 1);

    float4 a0 = make_float4(0.f, 0.f, 0.f, 0.f);
    float4 a1 = a0, a2 = a0, a3 = a0;
    int cnt = 0;
    if (single) {
        int ms = start[cs], me = start[cs + 1];
        cnt = me - ms;
        int nh = (cnt - half + 1) >> 1;      // this wave's member count (interleaved)
        for (int base = 0; base < nh; base += 64) {
            int j = base + lane;
            int id_l = 0;
            if (j < nh) id_l = member_nodes[ms + half + 2 * j];
            int kmax = nh - base; if (kmax > 64) kmax = 64;
            int k = 0;
            for (; k + 3 < kmax; k += 4) {
                int n0 = __shfl(id_l, k),     n1 = __shfl(id_l, k + 1);
                int n2 = __shfl(id_l, k + 2), n3 = __shfl(id_l, k + 3);
                const float4 x0 = *reinterpret_cast<const float4*>(&prop[(size_t)n0 * D + lane * 4]);
                const float4 x1 = *reinterpret_cast<const float4*>(&prop[(size_t)n1 * D + lane * 4]);
                const float4 x2 = *reinterpret_cast<const float4*>(&prop[(size_t)n2 * D + lane * 4]);
                const float4 x3 = *reinterpret_cast<const float4*>(&prop[(size_t)n3 * D + lane * 4]);
                a0.x += x0.x; a0.y += x0.y; a0.z += x0.z; a0.w += x0.w;
                a1.x += x1.x; a1.y += x1.y; a1.z += x1.z; a1.w += x1.w;
                a2.x += x2.x; a2.y += x2.y; a2.z += x2.z; a2.w += x2.w;
                a3.x += x3.x; a3.y += x3.y; a3.z += x3.z; a3.w += x3.w;
            }
            for (; k < kmax; ++k) {
                int n0 = __shfl(id_l, k);
                const float4 x0 = *reinterpret_cast<const float4*>(&prop[(size_t)n0 * D + lane * 4]);
                a0.x += x0.x; a0.y += x0.y; a0.z += x0.z; a0.w += x0.w;
            }
        }
        a0.x += a1.x + a2.x + a3.x;
        a0.y += a1.y + a2.y + a3.y;
        a0.z += a1.z + a2.z + a3.z;
        a0.w += a1.w + a2.w + a3.w;
    }
    part[wave][lane] = a0;
    __syncthreads();                      // uniform: exactly one barrier for all threads

    if (half == 0) {
        const float4 p = *reinterpret_cast<const float4*>(&prop[(size_t)v * D + lane * 4]);
        float4 second;
        if (single) {
            float4 o = part[wave ^ 1][lane];
            float inv = 1.0f / (float)cnt;
            second.x = (a0.x + o.x) * inv; second.y = (a0.y + o.y) * inv;
            second.z = (a0.z + o.z) * inv; second.w = (a0.w + o.w) * inv;
        } else if (cs == ce) {
            second = p;                   // no community: fallback
        } else {
            // general multi-community path (not hit on this data): serial mean+max
            float4 mx = make_float4(-INFINITY, -INFINITY, -INFINITY, -INFINITY);
            for (int c = cs; c < ce; ++c) {
                int ms = start[c], me = start[c + 1];
                float4 sum = make_float4(0.f, 0.f, 0.f, 0.f);
                for (int m = ms; m < me; ++m) {
                    int n0 = member_nodes[m];
                    const float4 x0 = *reinterpret_cast<const float4*>(&prop[(size_t)n0 * D + lane * 4]);
                    sum.x += x0.x; sum.y += x0.y; sum.z += x0.z; sum.w += x0.w;
                }
                float inv = 1.0f / (float)(me - ms);
                mx.x = fmaxf(mx.x, sum.x * inv); mx.y = fmaxf(mx.y, sum.y * inv);
                mx.z = fmaxf(mx.z, sum.z * inv); mx.w = fmaxf(mx.w, sum.w * inv);
            }
            second = mx;
        }
        float4 first;
        first.x = fmaxf(p.x, 0.f); first.y = fmaxf(p.y, 0.f);
        first.z = fmaxf(p.z, 0.f); first.w = fmaxf(p.w, 0.f);
        second.x = fmaxf(second.x, 0.f); second.y = fmaxf(second.y, 0.f);
        second.z = fmaxf(second.z, 0.f); second.w = fmaxf(second.w, 0.f);
        *reinterpret_cast<float4*>(&out[(size_t)v * (2 * D) + lane * 4]) = first;
        *reinterpret_cast<float4*>(&out[(size_t)v * (2 * D) + D + lane * 4]) = second;
    }
}

extern "C" void kernel_launch(void* const* d_in, const int* in_sizes, int n_in,
                              void* d_out, int out_size, void* d_ws, size_t ws_size,
                              hipStream_t stream) {
    const int*   edge_index   = (const int*)d_in[0];
    const float* X            = (const float*)d_in[1];
    const int*   member_nodes = (const int*)d_in[2];
    const int*   comm_ids     = (const int*)d_in[3];
    const int*   comm_owner   = (const int*)d_in[4];

    const int nnz_e = in_sizes[0] / 2;
    const int M     = in_sizes[2];
    const int C     = in_sizes[4];

    const int ND = N * D;
    int* ws = (int*)d_ws;
    int off = 0;
    int*   deg    = ws + off; off += N;
    int*   ell    = ws + off; off += N * KMAX;
    off = (off + 3) & ~3;                        // 16B align for float4
    float* y1     = (float*)(ws + off); off += ND;
    float* prop   = (float*)(ws + off); off += ND;
    int*   start  = ws + off; off += C + 1;
    int*   ostart = ws + off; off += N + 1;

    const int* row = edge_index;
    const int* col = edge_index + nnz_e;

    k_zero<<<(N + 255) / 256, 256, 0, stream>>>(deg);

    int maxt = nnz_e;
    if (C + 1 > maxt) maxt = C + 1;
    if (N + 1 > maxt) maxt = N + 1;
    k_build<<<(maxt + 255) / 256, 256, 0, stream>>>(
        row, col, nnz_e, deg, ell, comm_ids, M, C, start, comm_owner, ostart);

    k_spmm<<<ROW_BLOCKS, 256, 0, stream>>>(deg, ell, X, y1);
    k_spmm<<<ROW_BLOCKS, 256, 0, stream>>>(deg, ell, y1, prop);

    k_owner<<<N / 2, 256, 0, stream>>>(member_nodes, start, ostart, prop, (float*)d_out);
}

// Round 7
// 46.203 us; speedup vs baseline: 3.7061x; 1.0064x over previous
//
#include <hip/hip_runtime.h>
#include <math.h>

constexpr int N = 4096;
constexpr int D = 256;
constexpr int KMAX = 32;             // safe bound on directed degree (Poisson(~6))
constexpr int ROW_BLOCKS = N / 4;    // 4 waves (rows) per 256-thread block

// ---------------- zero degree counters ----------------
__global__ void k_zero(int* __restrict__ deg) {
    int i = blockIdx.x * blockDim.x + threadIdx.x;
    if (i < N) deg[i] = 0;
}

__device__ inline int lower_bound(const int* __restrict__ a, int n, int key) {
    int lo = 0, hi = n;
    while (lo < hi) {
        int mid = (lo + hi) >> 1;
        if (a[mid] < key) lo = mid + 1; else hi = mid;
    }
    return lo;
}

// ---------------- ELL build (atomic slot scatter) + segment bounds ----------------
__global__ void k_build(const int* __restrict__ row, const int* __restrict__ col,
                        int nnz_e, int* __restrict__ deg, int* __restrict__ ell,
                        const int* __restrict__ comm_ids, int M, int C,
                        int* __restrict__ start,
                        const int* __restrict__ comm_owner, int* __restrict__ ostart) {
    int t = blockIdx.x * blockDim.x + threadIdx.x;
    if (t < nnz_e) {
        int r = row[t], c = col[t];
        int pos = atomicAdd(&deg[r], 1);
        if (pos < KMAX) ell[r * KMAX + pos] = c;
    }
    if (t <= C) start[t] = lower_bound(comm_ids, M, t);
    if (t <= N) ostart[t] = lower_bound(comm_owner, C, t);
}

// ---------------- ELL SpMM (gather): wave per row, 2 independent accumulators ----------------
// If OUT != nullptr, also writes relu(acc) to OUT[r*2D .. r*2D+D) (fused first-half epilogue).
__global__ __launch_bounds__(256) void k_spmm(const int* __restrict__ deg,
                                              const int* __restrict__ ell,
                                              const float* __restrict__ X,
                                              float* __restrict__ Y,
                                              float* __restrict__ OUT) {
    int r = blockIdx.x * 4 + (threadIdx.x >> 6);
    int lane = threadIdx.x & 63;
    int dcnt = deg[r];
    int cnt = dcnt > KMAX ? KMAX : dcnt;
    float dr = rsqrtf((float)dcnt + 1.0f);

    const float4 xs = *reinterpret_cast<const float4*>(&X[(size_t)r * D + lane * 4]);
    float w0 = dr * dr;              // implicit self loop
    float4 acc0, acc1;
    acc0.x = w0 * xs.x; acc0.y = w0 * xs.y; acc0.z = w0 * xs.z; acc0.w = w0 * xs.w;
    acc1.x = 0.f; acc1.y = 0.f; acc1.z = 0.f; acc1.w = 0.f;

    int   c_l = 0;
    float w_l = 0.0f;
    if (lane < cnt) {
        c_l = ell[r * KMAX + lane];
        w_l = dr * rsqrtf((float)deg[c_l] + 1.0f);
    }
    int k = 0;
    for (; k + 1 < cnt; k += 2) {
        int   c0 = __shfl(c_l, k),     c1 = __shfl(c_l, k + 1);
        float u0 = __shfl(w_l, k),     u1 = __shfl(w_l, k + 1);
        const float4 x0 = *reinterpret_cast<const float4*>(&X[(size_t)c0 * D + lane * 4]);
        const float4 x1 = *reinterpret_cast<const float4*>(&X[(size_t)c1 * D + lane * 4]);
        acc0.x += u0 * x0.x; acc0.y += u0 * x0.y; acc0.z += u0 * x0.z; acc0.w += u0 * x0.w;
        acc1.x += u1 * x1.x; acc1.y += u1 * x1.y; acc1.z += u1 * x1.z; acc1.w += u1 * x1.w;
    }
    if (k < cnt) {
        int   c0 = __shfl(c_l, k);
        float u0 = __shfl(w_l, k);
        const float4 x0 = *reinterpret_cast<const float4*>(&X[(size_t)c0 * D + lane * 4]);
        acc0.x += u0 * x0.x; acc0.y += u0 * x0.y; acc0.z += u0 * x0.z; acc0.w += u0 * x0.w;
    }
    acc0.x += acc1.x; acc0.y += acc1.y; acc0.z += acc1.z; acc0.w += acc1.w;
    *reinterpret_cast<float4*>(&Y[(size_t)r * D + lane * 4]) = acc0;
    if (OUT) {
        float4 f;
        f.x = fmaxf(acc0.x, 0.f); f.y = fmaxf(acc0.y, 0.f);
        f.z = fmaxf(acc0.z, 0.f); f.w = fmaxf(acc0.w, 0.f);
        *reinterpret_cast<float4*>(&OUT[(size_t)r * (2 * D) + lane * 4]) = f;
    }
}

// ---------------- community mean (single comm per owner) -> out second half ----------------
// One node per 256-thread block; 4 waves split the member list 4-way interleaved.
__global__ __launch_bounds__(256) void k_owner(const int* __restrict__ member_nodes,
                                               const int* __restrict__ start,
                                               const int* __restrict__ ostart,
                                               const float* __restrict__ prop,
                                               float* __restrict__ out) {
    __shared__ float4 part[4][64];
    int wave = threadIdx.x >> 6;         // 0..3 : which quarter of the member list
    int lane = threadIdx.x & 63;
    int v = blockIdx.x;
    int cs = ostart[v], ce = ostart[v + 1];
    int single = (ce - cs == 1);

    float4 a0 = make_float4(0.f, 0.f, 0.f, 0.f);
    float4 a1 = a0, a2 = a0, a3 = a0;
    int cnt = 0;
    if (single) {
        int ms = start[cs], me = start[cs + 1];
        cnt = me - ms;
        int nh = cnt > wave ? ((cnt - wave + 3) >> 2) : 0;   // members at ms+wave+4*j
        for (int base = 0; base < nh; base += 64) {
            int j = base + lane;
            int id_l = 0;
            if (j < nh) id_l = member_nodes[ms + wave + 4 * j];
            int kmax = nh - base; if (kmax > 64) kmax = 64;
            int k = 0;
            for (; k + 3 < kmax; k += 4) {
                int n0 = __shfl(id_l, k),     n1 = __shfl(id_l, k + 1);
                int n2 = __shfl(id_l, k + 2), n3 = __shfl(id_l, k + 3);
                const float4 x0 = *reinterpret_cast<const float4*>(&prop[(size_t)n0 * D + lane * 4]);
                const float4 x1 = *reinterpret_cast<const float4*>(&prop[(size_t)n1 * D + lane * 4]);
                const float4 x2 = *reinterpret_cast<const float4*>(&prop[(size_t)n2 * D + lane * 4]);
                const float4 x3 = *reinterpret_cast<const float4*>(&prop[(size_t)n3 * D + lane * 4]);
                a0.x += x0.x; a0.y += x0.y; a0.z += x0.z; a0.w += x0.w;
                a1.x += x1.x; a1.y += x1.y; a1.z += x1.z; a1.w += x1.w;
                a2.x += x2.x; a2.y += x2.y; a2.z += x2.z; a2.w += x2.w;
                a3.x += x3.x; a3.y += x3.y; a3.z += x3.z; a3.w += x3.w;
            }
            for (; k < kmax; ++k) {
                int n0 = __shfl(id_l, k);
                const float4 x0 = *reinterpret_cast<const float4*>(&prop[(size_t)n0 * D + lane * 4]);
                a0.x += x0.x; a0.y += x0.y; a0.z += x0.z; a0.w += x0.w;
            }
        }
        a0.x += a1.x + a2.x + a3.x;
        a0.y += a1.y + a2.y + a3.y;
        a0.z += a1.z + a2.z + a3.z;
        a0.w += a1.w + a2.w + a3.w;
    }
    part[wave][lane] = a0;
    __syncthreads();                      // uniform barrier

    if (wave == 0) {
        float4 second;
        if (single) {
            float4 p1 = part[1][lane], p2 = part[2][lane], p3 = part[3][lane];
            float inv = 1.0f / (float)cnt;
            second.x = (a0.x + p1.x + p2.x + p3.x) * inv;
            second.y = (a0.y + p1.y + p2.y + p3.y) * inv;
            second.z = (a0.z + p1.z + p2.z + p3.z) * inv;
            second.w = (a0.w + p1.w + p2.w + p3.w) * inv;
        } else if (cs == ce) {
            second = *reinterpret_cast<const float4*>(&prop[(size_t)v * D + lane * 4]);
        } else {
            // general multi-community path (dead on this data, kept for safety)
            float4 mx = make_float4(-INFINITY, -INFINITY, -INFINITY, -INFINITY);
            for (int c = cs; c < ce; ++c) {
                int ms = start[c], me = start[c + 1];
                float4 sum = make_float4(0.f, 0.f, 0.f, 0.f);
                for (int m = ms; m < me; ++m) {
                    int n0 = member_nodes[m];
                    const float4 x0 = *reinterpret_cast<const float4*>(&prop[(size_t)n0 * D + lane * 4]);
                    sum.x += x0.x; sum.y += x0.y; sum.z += x0.z; sum.w += x0.w;
                }
                float inv = 1.0f / (float)(me - ms);
                mx.x = fmaxf(mx.x, sum.x * inv); mx.y = fmaxf(mx.y, sum.y * inv);
                mx.z = fmaxf(mx.z, sum.z * inv); mx.w = fmaxf(mx.w, sum.w * inv);
            }
            second = mx;
        }
        second.x = fmaxf(second.x, 0.f); second.y = fmaxf(second.y, 0.f);
        second.z = fmaxf(second.z, 0.f); second.w = fmaxf(second.w, 0.f);
        *reinterpret_cast<float4*>(&out[(size_t)v * (2 * D) + D + lane * 4]) = second;
    }
}

extern "C" void kernel_launch(void* const* d_in, const int* in_sizes, int n_in,
                              void* d_out, int out_size, void* d_ws, size_t ws_size,
                              hipStream_t stream) {
    const int*   edge_index   = (const int*)d_in[0];
    const float* X            = (const float*)d_in[1];
    const int*   member_nodes = (const int*)d_in[2];
    const int*   comm_ids     = (const int*)d_in[3];
    const int*   comm_owner   = (const int*)d_in[4];

    const int nnz_e = in_sizes[0] / 2;
    const int M     = in_sizes[2];
    const int C     = in_sizes[4];

    const int ND = N * D;
    int* ws = (int*)d_ws;
    int off = 0;
    int*   deg    = ws + off; off += N;
    int*   ell    = ws + off; off += N * KMAX;
    off = (off + 3) & ~3;                        // 16B align for float4
    float* y1     = (float*)(ws + off); off += ND;
    float* prop   = (float*)(ws + off); off += ND;
    int*   start  = ws + off; off += C + 1;
    int*   ostart = ws + off; off += N + 1;

    const int* row = edge_index;
    const int* col = edge_index + nnz_e;
    float* outp = (float*)d_out;

    k_zero<<<(N + 255) / 256, 256, 0, stream>>>(deg);

    int maxt = nnz_e;
    if (C + 1 > maxt) maxt = C + 1;
    if (N + 1 > maxt) maxt = N + 1;
    k_build<<<(maxt + 255) / 256, 256, 0, stream>>>(
        row, col, nnz_e, deg, ell, comm_ids, M, C, start, comm_owner, ostart);

    k_spmm<<<ROW_BLOCKS, 256, 0, stream>>>(deg, ell, X, y1, nullptr);
    k_spmm<<<ROW_BLOCKS, 256, 0, stream>>>(deg, ell, y1, prop, outp);  // + relu first half

    k_owner<<<N, 256, 0, stream>>>(member_nodes, start, ostart, prop, outp);
}

// Round 8
// 44.219 us; speedup vs baseline: 3.8724x; 1.0449x over previous
//
#include <hip/hip_runtime.h>
#include <math.h>

constexpr int N = 4096;
constexpr int D = 256;
constexpr int KMAX = 32;             // safe bound on directed degree (Poisson(~6))
constexpr int ROW_BLOCKS = N / 4;    // 4 waves (rows) per 256-thread block

// ---- bf16 helpers (RNE) ----
__device__ inline unsigned short f2bf(float f) {
    unsigned u = __float_as_uint(f);
    unsigned r = (u + 0x7FFFu + ((u >> 16) & 1u)) >> 16;
    return (unsigned short)r;
}
__device__ inline float bf2f(unsigned short h) {
    return __uint_as_float(((unsigned)h) << 16);
}
__device__ inline float4 bf4_to_f4(ushort4 s) {
    return make_float4(bf2f(s.x), bf2f(s.y), bf2f(s.z), bf2f(s.w));
}
__device__ inline ushort4 f4_to_bf4(float4 f) {
    ushort4 s; s.x = f2bf(f.x); s.y = f2bf(f.y); s.z = f2bf(f.z); s.w = f2bf(f.w);
    return s;
}

// ---------------- zero degree counters ----------------
__global__ void k_zero(int* __restrict__ deg) {
    int i = blockIdx.x * blockDim.x + threadIdx.x;
    if (i < N) deg[i] = 0;
}

__device__ inline int lower_bound(const int* __restrict__ a, int n, int key) {
    int lo = 0, hi = n;
    while (lo < hi) {
        int mid = (lo + hi) >> 1;
        if (a[mid] < key) lo = mid + 1; else hi = mid;
    }
    return lo;
}

// ---------------- ELL build (atomic slot scatter) + segment bounds ----------------
__global__ void k_build(const int* __restrict__ row, const int* __restrict__ col,
                        int nnz_e, int* __restrict__ deg, int* __restrict__ ell,
                        const int* __restrict__ comm_ids, int M, int C,
                        int* __restrict__ start,
                        const int* __restrict__ comm_owner, int* __restrict__ ostart) {
    int t = blockIdx.x * blockDim.x + threadIdx.x;
    if (t < nnz_e) {
        int r = row[t], c = col[t];
        int pos = atomicAdd(&deg[r], 1);
        if (pos < KMAX) ell[r * KMAX + pos] = c;
    }
    if (t <= C) start[t] = lower_bound(comm_ids, M, t);
    if (t <= N) ostart[t] = lower_bound(comm_owner, C, t);
}

// ---------------- SpMM pass 1: f32 X -> bf16 y1 ----------------
__global__ __launch_bounds__(256) void k_spmm1(const int* __restrict__ deg,
                                               const int* __restrict__ ell,
                                               const float* __restrict__ X,
                                               unsigned short* __restrict__ Ybf) {
    int r = blockIdx.x * 4 + (threadIdx.x >> 6);
    int lane = threadIdx.x & 63;
    int dcnt = deg[r];
    int cnt = dcnt > KMAX ? KMAX : dcnt;
    float dr = rsqrtf((float)dcnt + 1.0f);

    const float4 xs = *reinterpret_cast<const float4*>(&X[(size_t)r * D + lane * 4]);
    float w0 = dr * dr;              // implicit self loop
    float4 acc0, acc1;
    acc0.x = w0 * xs.x; acc0.y = w0 * xs.y; acc0.z = w0 * xs.z; acc0.w = w0 * xs.w;
    acc1.x = 0.f; acc1.y = 0.f; acc1.z = 0.f; acc1.w = 0.f;

    int   c_l = 0;
    float w_l = 0.0f;
    if (lane < cnt) {
        c_l = ell[r * KMAX + lane];
        w_l = dr * rsqrtf((float)deg[c_l] + 1.0f);
    }
    int k = 0;
    for (; k + 1 < cnt; k += 2) {
        int   c0 = __shfl(c_l, k),  c1 = __shfl(c_l, k + 1);
        float u0 = __shfl(w_l, k),  u1 = __shfl(w_l, k + 1);
        const float4 x0 = *reinterpret_cast<const float4*>(&X[(size_t)c0 * D + lane * 4]);
        const float4 x1 = *reinterpret_cast<const float4*>(&X[(size_t)c1 * D + lane * 4]);
        acc0.x += u0 * x0.x; acc0.y += u0 * x0.y; acc0.z += u0 * x0.z; acc0.w += u0 * x0.w;
        acc1.x += u1 * x1.x; acc1.y += u1 * x1.y; acc1.z += u1 * x1.z; acc1.w += u1 * x1.w;
    }
    if (k < cnt) {
        int   c0 = __shfl(c_l, k);
        float u0 = __shfl(w_l, k);
        const float4 x0 = *reinterpret_cast<const float4*>(&X[(size_t)c0 * D + lane * 4]);
        acc0.x += u0 * x0.x; acc0.y += u0 * x0.y; acc0.z += u0 * x0.z; acc0.w += u0 * x0.w;
    }
    acc0.x += acc1.x; acc0.y += acc1.y; acc0.z += acc1.z; acc0.w += acc1.w;
    *reinterpret_cast<ushort4*>(&Ybf[(size_t)r * D + lane * 4]) = f4_to_bf4(acc0);
}

// ---------------- SpMM pass 2: bf16 y1 -> bf16 prop + f32 relu first-half out ----------------
__global__ __launch_bounds__(256) void k_spmm2(const int* __restrict__ deg,
                                               const int* __restrict__ ell,
                                               const unsigned short* __restrict__ Ybf,
                                               unsigned short* __restrict__ Pbf,
                                               float* __restrict__ OUT) {
    int r = blockIdx.x * 4 + (threadIdx.x >> 6);
    int lane = threadIdx.x & 63;
    int dcnt = deg[r];
    int cnt = dcnt > KMAX ? KMAX : dcnt;
    float dr = rsqrtf((float)dcnt + 1.0f);

    const float4 xs = bf4_to_f4(*reinterpret_cast<const ushort4*>(&Ybf[(size_t)r * D + lane * 4]));
    float w0 = dr * dr;              // implicit self loop
    float4 acc0, acc1;
    acc0.x = w0 * xs.x; acc0.y = w0 * xs.y; acc0.z = w0 * xs.z; acc0.w = w0 * xs.w;
    acc1.x = 0.f; acc1.y = 0.f; acc1.z = 0.f; acc1.w = 0.f;

    int   c_l = 0;
    float w_l = 0.0f;
    if (lane < cnt) {
        c_l = ell[r * KMAX + lane];
        w_l = dr * rsqrtf((float)deg[c_l] + 1.0f);
    }
    int k = 0;
    for (; k + 1 < cnt; k += 2) {
        int   c0 = __shfl(c_l, k),  c1 = __shfl(c_l, k + 1);
        float u0 = __shfl(w_l, k),  u1 = __shfl(w_l, k + 1);
        const float4 x0 = bf4_to_f4(*reinterpret_cast<const ushort4*>(&Ybf[(size_t)c0 * D + lane * 4]));
        const float4 x1 = bf4_to_f4(*reinterpret_cast<const ushort4*>(&Ybf[(size_t)c1 * D + lane * 4]));
        acc0.x += u0 * x0.x; acc0.y += u0 * x0.y; acc0.z += u0 * x0.z; acc0.w += u0 * x0.w;
        acc1.x += u1 * x1.x; acc1.y += u1 * x1.y; acc1.z += u1 * x1.z; acc1.w += u1 * x1.w;
    }
    if (k < cnt) {
        int   c0 = __shfl(c_l, k);
        float u0 = __shfl(w_l, k);
        const float4 x0 = bf4_to_f4(*reinterpret_cast<const ushort4*>(&Ybf[(size_t)c0 * D + lane * 4]));
        acc0.x += u0 * x0.x; acc0.y += u0 * x0.y; acc0.z += u0 * x0.z; acc0.w += u0 * x0.w;
    }
    acc0.x += acc1.x; acc0.y += acc1.y; acc0.z += acc1.z; acc0.w += acc1.w;

    *reinterpret_cast<ushort4*>(&Pbf[(size_t)r * D + lane * 4]) = f4_to_bf4(acc0);
    float4 f;
    f.x = fmaxf(acc0.x, 0.f); f.y = fmaxf(acc0.y, 0.f);
    f.z = fmaxf(acc0.z, 0.f); f.w = fmaxf(acc0.w, 0.f);
    *reinterpret_cast<float4*>(&OUT[(size_t)r * (2 * D) + lane * 4]) = f;
}

// ---------------- community mean (single comm per owner) -> out second half ----------------
// One node per 256-thread block; 4 waves split the member list 4-way interleaved; bf16 gathers.
__global__ __launch_bounds__(256) void k_owner(const int* __restrict__ member_nodes,
                                               const int* __restrict__ start,
                                               const int* __restrict__ ostart,
                                               const unsigned short* __restrict__ Pbf,
                                               float* __restrict__ out) {
    __shared__ float4 part[4][64];
    int wave = threadIdx.x >> 6;         // 0..3 : which quarter of the member list
    int lane = threadIdx.x & 63;
    int v = blockIdx.x;
    int cs = ostart[v], ce = ostart[v + 1];
    int single = (ce - cs == 1);

    float4 a0 = make_float4(0.f, 0.f, 0.f, 0.f);
    float4 a1 = a0, a2 = a0, a3 = a0;
    int cnt = 0;
    if (single) {
        int ms = start[cs], me = start[cs + 1];
        cnt = me - ms;
        int nh = cnt > wave ? ((cnt - wave + 3) >> 2) : 0;   // members at ms+wave+4*j
        for (int base = 0; base < nh; base += 64) {
            int j = base + lane;
            int id_l = 0;
            if (j < nh) id_l = member_nodes[ms + wave + 4 * j];
            int kmax = nh - base; if (kmax > 64) kmax = 64;
            int k = 0;
            for (; k + 3 < kmax; k += 4) {
                int n0 = __shfl(id_l, k),     n1 = __shfl(id_l, k + 1);
                int n2 = __shfl(id_l, k + 2), n3 = __shfl(id_l, k + 3);
                const float4 x0 = bf4_to_f4(*reinterpret_cast<const ushort4*>(&Pbf[(size_t)n0 * D + lane * 4]));
                const float4 x1 = bf4_to_f4(*reinterpret_cast<const ushort4*>(&Pbf[(size_t)n1 * D + lane * 4]));
                const float4 x2 = bf4_to_f4(*reinterpret_cast<const ushort4*>(&Pbf[(size_t)n2 * D + lane * 4]));
                const float4 x3 = bf4_to_f4(*reinterpret_cast<const ushort4*>(&Pbf[(size_t)n3 * D + lane * 4]));
                a0.x += x0.x; a0.y += x0.y; a0.z += x0.z; a0.w += x0.w;
                a1.x += x1.x; a1.y += x1.y; a1.z += x1.z; a1.w += x1.w;
                a2.x += x2.x; a2.y += x2.y; a2.z += x2.z; a2.w += x2.w;
                a3.x += x3.x; a3.y += x3.y; a3.z += x3.z; a3.w += x3.w;
            }
            for (; k < kmax; ++k) {
                int n0 = __shfl(id_l, k);
                const float4 x0 = bf4_to_f4(*reinterpret_cast<const ushort4*>(&Pbf[(size_t)n0 * D + lane * 4]));
                a0.x += x0.x; a0.y += x0.y; a0.z += x0.z; a0.w += x0.w;
            }
        }
        a0.x += a1.x + a2.x + a3.x;
        a0.y += a1.y + a2.y + a3.y;
        a0.z += a1.z + a2.z + a3.z;
        a0.w += a1.w + a2.w + a3.w;
    }
    part[wave][lane] = a0;
    __syncthreads();                      // uniform barrier

    if (wave == 0) {
        float4 second;
        if (single) {
            float4 p1 = part[1][lane], p2 = part[2][lane], p3 = part[3][lane];
            float inv = 1.0f / (float)cnt;
            second.x = (a0.x + p1.x + p2.x + p3.x) * inv;
            second.y = (a0.y + p1.y + p2.y + p3.y) * inv;
            second.z = (a0.z + p1.z + p2.z + p3.z) * inv;
            second.w = (a0.w + p1.w + p2.w + p3.w) * inv;
        } else if (cs == ce) {
            second = bf4_to_f4(*reinterpret_cast<const ushort4*>(&Pbf[(size_t)v * D + lane * 4]));
        } else {
            // general multi-community path (dead on this data, kept for safety)
            float4 mx = make_float4(-INFINITY, -INFINITY, -INFINITY, -INFINITY);
            for (int c = cs; c < ce; ++c) {
                int ms = start[c], me = start[c + 1];
                float4 sum = make_float4(0.f, 0.f, 0.f, 0.f);
                for (int m = ms; m < me; ++m) {
                    int n0 = member_nodes[m];
                    const float4 x0 = bf4_to_f4(*reinterpret_cast<const ushort4*>(&Pbf[(size_t)n0 * D + lane * 4]));
                    sum.x += x0.x; sum.y += x0.y; sum.z += x0.z; sum.w += x0.w;
                }
                float inv = 1.0f / (float)(me - ms);
                mx.x = fmaxf(mx.x, sum.x * inv); mx.y = fmaxf(mx.y, sum.y * inv);
                mx.z = fmaxf(mx.z, sum.z * inv); mx.w = fmaxf(mx.w, sum.w * inv);
            }
            second = mx;
        }
        second.x = fmaxf(second.x, 0.f); second.y = fmaxf(second.y, 0.f);
        second.z = fmaxf(second.z, 0.f); second.w = fmaxf(second.w, 0.f);
        *reinterpret_cast<float4*>(&out[(size_t)v * (2 * D) + D + lane * 4]) = second;
    }
}

extern "C" void kernel_launch(void* const* d_in, const int* in_sizes, int n_in,
                              void* d_out, int out_size, void* d_ws, size_t ws_size,
                              hipStream_t stream) {
    const int*   edge_index   = (const int*)d_in[0];
    const float* X            = (const float*)d_in[1];
    const int*   member_nodes = (const int*)d_in[2];
    const int*   comm_ids     = (const int*)d_in[3];
    const int*   comm_owner   = (const int*)d_in[4];

    const int nnz_e = in_sizes[0] / 2;
    const int M     = in_sizes[2];
    const int C     = in_sizes[4];

    const int ND = N * D;
    int* ws = (int*)d_ws;
    int off = 0;
    int*   deg    = ws + off; off += N;
    int*   ell    = ws + off; off += N * KMAX;
    off = (off + 3) & ~3;                        // 16B align
    unsigned short* y1bf = (unsigned short*)(ws + off); off += ND / 2;  // bf16 y1 (2 MB)
    unsigned short* pbf  = (unsigned short*)(ws + off); off += ND / 2;  // bf16 prop (2 MB)
    int*   start  = ws + off; off += C + 1;
    int*   ostart = ws + off; off += N + 1;

    const int* row = edge_index;
    const int* col = edge_index + nnz_e;
    float* outp = (float*)d_out;

    k_zero<<<(N + 255) / 256, 256, 0, stream>>>(deg);

    int maxt = nnz_e;
    if (C + 1 > maxt) maxt = C + 1;
    if (N + 1 > maxt) maxt = N + 1;
    k_build<<<(maxt + 255) / 256, 256, 0, stream>>>(
        row, col, nnz_e, deg, ell, comm_ids, M, C, start, comm_owner, ostart);

    k_spmm1<<<ROW_BLOCKS, 256, 0, stream>>>(deg, ell, X, y1bf);
    k_spmm2<<<ROW_BLOCKS, 256, 0, stream>>>(deg, ell, y1bf, pbf, outp);

    k_owner<<<N, 256, 0, stream>>>(member_nodes, start, ostart, pbf, outp);
}